// Round 6
// baseline (176.697 us; speedup 1.0000x reference)
//
#include <hip/hip_runtime.h>

#define N_Q   16384
#define C_DIM 128
#define S_CAM 6
#define M_VAL 1400   // 28*50
#define D_Z   8
#define HF    28
#define WF    50
#define QPB   8      // gather: queries per block; 32 lanes/query
#define VP_BLOCKS 1050   // (S_CAM*M_VAL)/8
#define QP_BLOCKS 512    // N_Q/32

typedef float f32x2 __attribute__((ext_vector_type(2)));

__device__ __forceinline__ bool mask_any(const unsigned char* __restrict__ mask,
                                         int mflag, size_t mbase){
  if(mflag==0){
    int any=0;
    #pragma unroll
    for(int d=0;d<D_Z;d++) any |= mask[mbase+d];
    return any!=0;
  } else if(mflag==1){
    const int* mp = (const int*)mask;  int any=0;
    #pragma unroll
    for(int d=0;d<D_Z;d++) any |= mp[mbase+d];
    return any!=0;
  } else {
    const long long* mp = (const long long*)mask;  long long any=0;
    #pragma unroll
    for(int d=0;d<D_Z;d++) any |= mp[mbase+d];
    return any!=0;
  }
}

// fp8x16 corner accumulate as f32x2 pairs -> v_pk_fma_f32.
__device__ __forceinline__ void corner_acc(const uint4 cv, const float wgt,
                                           f32x2* __restrict__ acc2){
  const f32x2 w2 = {wgt, wgt};
  const unsigned dw[4] = {cv.x, cv.y, cv.z, cv.w};
  #pragma unroll
  for(int j=0;j<4;j++){
    acc2[j*2+0] += w2 * __builtin_amdgcn_cvt_pk_f32_fp8(dw[j], false);
    acc2[j*2+1] += w2 * __builtin_amdgcn_cvt_pk_f32_fp8(dw[j], true);
  }
}

__device__ __forceinline__ void fma4(float4& a, const float4 t,
                                     const float4 w0, const float4 w1,
                                     const float4 w2, const float4 w3){
  a.x += t.x*w0.x + t.y*w1.x + t.z*w2.x + t.w*w3.x;
  a.y += t.x*w0.y + t.y*w1.y + t.z*w2.y + t.w*w3.y;
  a.z += t.x*w0.z + t.y*w1.z + t.z*w2.z + t.w*w3.z;
  a.w += t.x*w0.w + t.y*w1.w + t.z*w2.w + t.w*w3.w;
}

__device__ __forceinline__ void shfl4_add32(float4& a){
  a.x += __shfl_xor(a.x, 32);
  a.y += __shfl_xor(a.y, 32);
  a.z += __shfl_xor(a.z, 32);
  a.w += __shfl_xor(a.w, 32);
}

__device__ __forceinline__ float4 shfl4_xor(float4 v, int m){
  return make_float4(__shfl_xor(v.x,m), __shfl_xor(v.y,m),
                     __shfl_xor(v.z,m), __shfl_xor(v.w,m));
}

__device__ __forceinline__ float4 f4add(float4 a, float4 b){
  return make_float4(a.x+b.x, a.y+b.y, a.z+b.z, a.w+b.w);
}

// ---------------------------------------------------------------------------
// K1 = value-proj (blocks 0..1049) UNION q-proj (blocks 1050..1561).
// R6: q-proj amortization doubled -- 32 queries/block, 8/wave (Wo/Wa read
// once per 8 queries instead of per 4). offs -> out cols 0..63, attns ->
// out cols 64..95 (dead OUT rows as staging; workspace stays ~1.08MB).
// ---------------------------------------------------------------------------
__global__ __launch_bounds__(256)
void prep_kernel(const float* __restrict__ value,
                 const float* __restrict__ Wv,
                 const float* __restrict__ bv,
                 unsigned char* __restrict__ v8,
                 const unsigned char* __restrict__ mask,
                 int* __restrict__ flag,
                 const float* __restrict__ query,
                 const float* __restrict__ query_pos,
                 const float* __restrict__ Wo, const float* __restrict__ bo,
                 const float* __restrict__ Wa, const float* __restrict__ ba,
                 float* __restrict__ out){
  __shared__ float smem[4096];               // vproj: tile+part (2048); qproj: qtile[32][128]
  __shared__ float lbuf[32][32];             // qproj: raw logits for softmax
  __shared__ int s_cntA, s_cntB;
  const int tid = threadIdx.x;
  const int bid = blockIdx.x;

  if(bid < VP_BLOCKS){
    // ---------------- value projection -> fp8 ----------------
    float* tile = smem;                      // [8][128]
    float* part = smem + 1024;               // [8][128]
    const int c   = tid & 127;
    const int kh  = tid >> 7;
    const int r0  = bid * 8;
    if(bid==0 && tid==0){ s_cntA=0; s_cntB=0; }
    {
      const float4* src = (const float4*)(value + (size_t)r0*C_DIM);
      ((float4*)tile)[tid] = src[tid];
    }
    __syncthreads();
    float acc[8];
    {
      const float bias = kh ? 0.f : bv[c];
      #pragma unroll
      for(int r=0;r<8;r++) acc[r]=bias;
    }
    {
      const float* Wp = Wv + (size_t)kh*64*C_DIM + c;
      const int k00 = kh*64;
      for(int k0=0;k0<64;k0+=4){
        const float w0 = Wp[0];
        const float w1 = Wp[C_DIM];
        const float w2 = Wp[2*C_DIM];
        const float w3 = Wp[3*C_DIM];
        #pragma unroll
        for(int r=0;r<8;r++){
          const float4 t = *(const float4*)&tile[r*C_DIM + k00+k0];
          acc[r] += t.x*w0 + t.y*w1 + t.z*w2 + t.w*w3;
        }
        Wp += 4*C_DIM;
      }
    }
    if(kh){
      #pragma unroll
      for(int r=0;r<8;r++) part[r*C_DIM + c] = acc[r];
    }
    __syncthreads();
    if(!kh){
      #pragma unroll
      for(int r=0;r<8;r++){
        const float v = acc[r] + part[r*C_DIM + c];
        const int pk = __builtin_amdgcn_cvt_pk_fp8_f32(v, v, 0, false);
        v8[(size_t)(r0+r)*C_DIM + c] = (unsigned char)(pk & 0xff);
      }
    }
    if(bid==0){
      int a=0, b=0;
      for(int i=tid;i<1024;i+=256){
        const unsigned char v = mask[i];
        if(((i&3)!=0) && v) a=1;
        if(((i&7)==4) && v) b=1;
      }
      if(a) atomicOr(&s_cntA,1);
      if(b) atomicOr(&s_cntB,1);
      __syncthreads();
      if(tid==0) flag[0] = s_cntA ? 0 : (s_cntB ? 1 : 2);
    }
  } else {
    // ---------------- query projections + softmax (32 q/block) ----------------
    const int qb = bid - VP_BLOCKS;
    const int n0 = qb * 32;
    float* qtile = smem;                     // [32][128]
    {
      const float4* qa = (const float4*)(query     + (size_t)n0*C_DIM);
      const float4* qp = (const float4*)(query_pos + (size_t)n0*C_DIM);
      #pragma unroll
      for(int j=0;j<4;j++){
        const int idx = tid + 256*j;
        const float4 A = qa[idx], B = qp[idx];
        *(float4*)&qtile[idx*4] = make_float4(A.x+B.x, A.y+B.y, A.z+B.z, A.w+B.w);
      }
    }
    __syncthreads();
    const int wi = tid >> 6;                 // wave: queries wi*8 .. wi*8+7
    const int ln = tid & 63;
    const int kh = ln >> 5;                  // k-half
    const int cg = ln & 31;                  // col-group
    float4 a[8];
    #pragma unroll
    for(int q=0;q<8;q++) a[q]=make_float4(0.f,0.f,0.f,0.f);
    if(cg < 24){
      const float* Wp; int stride; const float* bptr;
      if(cg < 16){ Wp = Wo + cg*4;      stride = 64; bptr = &bo[cg*4]; }
      else       { Wp = Wa + (cg-16)*4; stride = 32; bptr = &ba[(cg-16)*4]; }
      if(kh==0){
        const float4 bb = *(const float4*)bptr;
        #pragma unroll
        for(int q=0;q<8;q++) a[q]=bb;
      }
      Wp += (size_t)kh*64*stride;
      const float* qbase = &qtile[(size_t)wi*8*C_DIM + kh*64];
      #pragma unroll 4
      for(int k0=0;k0<64;k0+=4){
        const float4 w0 = *(const float4*)&Wp[0];
        const float4 w1 = *(const float4*)&Wp[stride];
        const float4 w2 = *(const float4*)&Wp[2*stride];
        const float4 w3 = *(const float4*)&Wp[3*stride];
        #pragma unroll
        for(int q=0;q<8;q++)
          fma4(a[q], *(const float4*)&qbase[q*C_DIM + k0], w0,w1,w2,w3);
        Wp += 4*stride;
      }
    }
    #pragma unroll
    for(int q=0;q<8;q++) shfl4_add32(a[q]);  // both kh halves now hold full sums
    if(cg < 16){
      const int c0 = cg*4;
      const int rb = n0 + wi*8 + (kh?4:0);   // kh=0 stores q0..3, kh=1 q4..7
      #pragma unroll
      for(int i=0;i<4;i++){
        const float4 v = kh ? a[4+i] : a[i];
        *(float4*)&out[(size_t)(rb+i)*C_DIM + c0] = v;
      }
    } else if(cg < 24){
      const int c0 = (cg-16)*4;
      const int rb = wi*8 + (kh?4:0);
      #pragma unroll
      for(int i=0;i<4;i++){
        const float4 v = kh ? a[4+i] : a[i];
        *(float4*)&lbuf[rb+i][c0] = v;
      }
    }
    __syncthreads();
    if(tid < 128){                           // softmax over P=8: (q, h)
      const int q = tid >> 2, h = tid & 3;
      const float* L = &lbuf[q][h*8];
      float mx = L[0];
      #pragma unroll
      for(int p=1;p<8;p++) mx = fmaxf(mx, L[p]);
      float e[8], ssum = 0.f;
      #pragma unroll
      for(int p=0;p<8;p++){ e[p] = __expf(L[p]-mx); ssum += e[p]; }
      const float inv = 1.f/ssum;
      float* dst = &out[(size_t)(n0+q)*C_DIM + 64 + h*8];
      *(float4*)dst     = make_float4(e[0]*inv, e[1]*inv, e[2]*inv, e[3]*inv);
      *(float4*)(dst+4) = make_float4(e[4]*inv, e[5]*inv, e[6]*inv, e[7]*inv);
    }
  }
}

// ---------------------------------------------------------------------------
// K2: gather + out-proj fused. R6: outproj re-structured as OUTPUT-SPLIT --
// wave w owns a 32-col stripe of Wout; lane=(kslot 0..7, cg 0..7); one f4
// load per lane covers 8 k-rows x 32 cols, so each block reads Wout exactly
// once (64 VMEM instrs vs 256 in R5 -> ~-10us of TA time at 16cy/instr).
// k-partials reduced to lane kslot==q via a 3-round reduce-scatter
// (shfl_xor 32,16,8; 28 shuffles, all static indexing). Costs one extra
// __syncthreads (waves read all 8 slot rows). Scatter phase unchanged -- it
// sits at its ~49us cache-line-rate floor (6.29M fully-consumed 64B lines).
// ---------------------------------------------------------------------------
__global__ __launch_bounds__(256)
void gather_kernel(const unsigned char* __restrict__ v8,
                   const float* __restrict__ ref,
                   const unsigned char* __restrict__ mask,
                   const int* __restrict__ flag,
                   const float* __restrict__ query,
                   const float* __restrict__ Wout,
                   const float* __restrict__ bout,
                   float* __restrict__ out){
  __shared__ float  qs[QPB][C_DIM+4];        // slot rows
  __shared__ float  offs[QPB][68];           // 68 mod 32 = 4
  __shared__ float  attns[QPB][36];
  __shared__ float2 refs[QPB][S_CAM*D_Z+1];  // 49 f2 rows
  __shared__ int    activ[QPB][S_CAM];
  __shared__ float  cinv[QPB];

  const int tid = threadIdx.x;
  const int n0  = blockIdx.x * QPB;
  const int mflag = flag[0];
  const int qi = tid >> 5;                   // query in block
  const int l  = tid & 31;                   // lane within query group

  // ---- staging: offs/attns from out rows (cols 0..95), refs, activ, cinv ----
  if(tid < 192){                             // 8q x 24 f4 = offs(16) + attns(8)
    const int q = tid/24, j = tid%24;
    const float4 v = *(const float4*)&out[(size_t)(n0+q)*C_DIM + j*4];
    if(j<16) *(float4*)&offs[q][j*4] = v;
    else     *(float4*)&attns[q][(j-16)*4] = v;
  }
  {
    const int q = tid/48, r = tid%48;        // r = s*8+p
    refs[q][r] = ((const float2*)ref)[((size_t)(r>>3)*N_Q + (n0+q))*D_Z + (r&7)];
    if(tid < 128){
      const int e1 = tid + 256;
      const int q1 = e1/48, r1 = e1%48;
      refs[q1][r1] = ((const float2*)ref)[((size_t)(r1>>3)*N_Q + (n0+q1))*D_Z + (r1&7)];
    }
  }
  if(tid < QPB*S_CAM){
    const int q2 = tid / S_CAM, s = tid % S_CAM;
    activ[q2][s] = mask_any(mask, mflag, ((size_t)s*N_Q + (n0+q2))*D_Z) ? 1 : 0;
  } else if(tid < QPB*S_CAM + QPB){
    const int q2 = tid - QPB*S_CAM;
    int c = 0;
    #pragma unroll
    for(int s=0;s<S_CAM;s++)
      c += mask_any(mask, mflag, ((size_t)s*N_Q + (n0+q2))*D_Z) ? 1 : 0;
    cinv[q2] = 1.f / fmaxf((float)c, 1.f);
  }
  __syncthreads();                           // staging reads done before out overwrite

  // ---- gather: 3 cams x 4 points per lane ----
  const int pg  = l >> 4;                    // points pg*4 .. pg*4+3
  const int sg  = (l >> 3) & 1;              // cams sg*3 .. sg*3+2
  const int ll  = l & 7;                     // 16-ch group
  const int gch = ll*16;
  const int gh  = ll >> 1;                   // head (32 ch/head)
  f32x2 acc2[8];
  #pragma unroll
  for(int i=0;i<8;i++) acc2[i] = (f32x2){0.f, 0.f};

  for(int s=sg*3; s<sg*3+3; s++){
    if(!activ[qi][s]) continue;
    const unsigned char* vb = v8 + (size_t)s*M_VAL*C_DIM + gch;
    #pragma unroll 2
    for(int pp=0;pp<4;pp++){                 // point p <-> z-anchor d=p (P//D==1)
      const int p = pg*4 + pp;
      const float2 r2 = refs[qi][s*8+p];
      const float ox = offs[qi][gh*16+p*2+0];
      const float oy = offs[qi][gh*16+p*2+1];
      const float x = fmaf(r2.x, (float)WF, ox - 0.5f);
      const float y = fmaf(r2.y, (float)HF, oy - 0.5f);
      const float x0f = floorf(x), y0f = floorf(y);
      const float fx = x - x0f,    fy = y - y0f;
      const int x0 = (int)x0f, y0 = (int)y0f;
      const int x1 = x0+1,     y1 = y0+1;
      const float at = attns[qi][gh*8+p];
      const float wx0 = (x0>=0 && x0<WF) ? (1.f-fx) : 0.f;
      const float wx1 = (x1>=0 && x1<WF) ? fx       : 0.f;
      const float wy0 = ((y0>=0 && y0<HF) ? (1.f-fy) : 0.f) * at;
      const float wy1 = ((y1>=0 && y1<HF) ? fy       : 0.f) * at;
      const int x0c = min(max(x0,0), WF-1), x1c = min(max(x1,0), WF-1);
      const int y0c = min(max(y0,0), HF-1), y1c = min(max(y1,0), HF-1);
      const float w00 = wx0*wy0, w01 = wx1*wy0, w10 = wx0*wy1, w11 = wx1*wy1;
      const uint4 c00 = *(const uint4*)(vb + (size_t)(y0c*WF+x0c)*C_DIM);
      const uint4 c01 = *(const uint4*)(vb + (size_t)(y0c*WF+x1c)*C_DIM);
      const uint4 c10 = *(const uint4*)(vb + (size_t)(y1c*WF+x0c)*C_DIM);
      const uint4 c11 = *(const uint4*)(vb + (size_t)(y1c*WF+x1c)*C_DIM);
      corner_acc(c00, w00, acc2);
      corner_acc(c01, w01, acc2);
      corner_acc(c10, w10, acc2);
      corner_acc(c11, w11, acc2);
    }
  }

  // ---- merge 4 (pg,sg) partials; slot rows -> LDS ----
  float* accf = (float*)acc2;
  #pragma unroll
  for(int i=0;i<16;i++) accf[i] += __shfl_xor(accf[i], 16);  // merge pt halves
  #pragma unroll
  for(int i=0;i<16;i++) accf[i] += __shfl_xor(accf[i], 8);   // merge cam halves
  if(l < 8){
    const float inv = cinv[qi];
    #pragma unroll
    for(int i=0;i<4;i++)
      *(float4*)&qs[qi][gch+i*4] = make_float4(accf[i*4+0]*inv, accf[i*4+1]*inv,
                                               accf[i*4+2]*inv, accf[i*4+3]*inv);
  }
  __syncthreads();                           // all 8 slot rows visible to all waves

  // ---- out-proj + bias + residual: output-split, Wout read once/block ----
  {
    const int wi2   = tid >> 6;              // wave -> col stripe wi2*32
    const int ln    = tid & 63;
    const int kslot = ln >> 3;               // k-subset AND final store-query
    const int cg    = ln & 7;                // f4 col within stripe
    const int c0    = wi2*32 + cg*4;
    float4 a[8];
    #pragma unroll
    for(int q=0;q<8;q++) a[q]=make_float4(0.f,0.f,0.f,0.f);
    const float* Wp = Wout + (size_t)kslot*C_DIM + c0;
    #pragma unroll 4
    for(int t=0;t<16;t++){
      const float4 w = *(const float4*)Wp;   // Wout[8t+kslot][c0..c0+3]
      const int k = 8*t + kslot;
      #pragma unroll
      for(int q=0;q<8;q++){
        const float s = qs[q][k];
        a[q].x += s*w.x; a[q].y += s*w.y; a[q].z += s*w.z; a[q].w += s*w.w;
      }
      Wp += 8*C_DIM;
    }
    // reduce-scatter over kslot lanes: query q ends at lane kslot==q.
    // mask 32 <-> q bit2
    const bool b2 = (kslot & 4) != 0;
    float4 s0 = b2 ? a[0] : a[4];            // send = half we don't keep
    float4 s1 = b2 ? a[1] : a[5];
    float4 s2 = b2 ? a[2] : a[6];
    float4 s3 = b2 ? a[3] : a[7];
    s0 = shfl4_xor(s0,32); s1 = shfl4_xor(s1,32);
    s2 = shfl4_xor(s2,32); s3 = shfl4_xor(s3,32);
    float4 r0 = f4add(b2 ? a[4] : a[0], s0);
    float4 r1 = f4add(b2 ? a[5] : a[1], s1);
    float4 r2 = f4add(b2 ? a[6] : a[2], s2);
    float4 r3 = f4add(b2 ? a[7] : a[3], s3);
    // mask 16 <-> q bit1
    const bool b1 = (kslot & 2) != 0;
    float4 t0 = b1 ? r0 : r2;
    float4 t1 = b1 ? r1 : r3;
    t0 = shfl4_xor(t0,16); t1 = shfl4_xor(t1,16);
    float4 k0 = f4add(b1 ? r2 : r0, t0);
    float4 k1 = f4add(b1 ? r3 : r1, t1);
    // mask 8 <-> q bit0
    const bool b0c = (kslot & 1) != 0;
    float4 u0 = b0c ? k0 : k1;
    u0 = shfl4_xor(u0,8);
    float4 fin = f4add(b0c ? k1 : k0, u0);
    // lane stores query kslot, cols c0..c0+3 (+bias+residual)
    const float4 bb = *(const float4*)&bout[c0];
    const float4 rq = *(const float4*)&query[(size_t)(n0+kslot)*C_DIM + c0];
    *(float4*)&out[(size_t)(n0+kslot)*C_DIM + c0] =
      make_float4(fin.x+bb.x+rq.x, fin.y+bb.y+rq.y,
                  fin.z+bb.z+rq.z, fin.w+bb.w+rq.w);
  }
}

extern "C" void kernel_launch(void* const* d_in, const int* in_sizes, int n_in,
                              void* d_out, int out_size, void* d_ws, size_t ws_size,
                              hipStream_t stream){
  const float* query     = (const float*)d_in[0];
  const float* query_pos = (const float*)d_in[1];
  const float* value     = (const float*)d_in[2];
  const float* ref       = (const float*)d_in[3];
  const unsigned char* mask = (const unsigned char*)d_in[4];
  const float* Wv   = (const float*)d_in[5];
  const float* bv   = (const float*)d_in[6];
  const float* Wo   = (const float*)d_in[7];
  const float* bo   = (const float*)d_in[8];
  const float* Wa   = (const float*)d_in[9];
  const float* ba   = (const float*)d_in[10];
  const float* Wout = (const float*)d_in[11];
  const float* bout = (const float*)d_in[12];
  float* out = (float*)d_out;

  int* flag = (int*)d_ws;
  unsigned char* v8 = (unsigned char*)((char*)d_ws + 64);  // 1,075,200 B (proven footprint)

  prep_kernel<<<VP_BLOCKS + QP_BLOCKS, 256, 0, stream>>>(
      value, Wv, bv, v8, mask, flag, query, query_pos, Wo, bo, Wa, ba, out);
  gather_kernel<<<N_Q/QPB, 256, 0, stream>>>(v8, ref, mask, flag,
                                             query, Wout, bout, out);
}

// Round 7
// 175.397 us; speedup vs baseline: 1.0074x; 1.0074x over previous
//
#include <hip/hip_runtime.h>

#define N_Q   16384
#define C_DIM 128
#define S_CAM 6
#define M_VAL 1400   // 28*50
#define D_Z   8
#define HF    28
#define WF    50
#define QPB   8      // gather: queries per block; 32 lanes/query
#define VP_BLOCKS 525    // (S_CAM*M_VAL)/16
#define QP_BLOCKS 512    // N_Q/32

typedef float f32x2 __attribute__((ext_vector_type(2)));

__device__ __forceinline__ bool mask_any(const unsigned char* __restrict__ mask,
                                         int mflag, size_t mbase){
  if(mflag==0){
    int any=0;
    #pragma unroll
    for(int d=0;d<D_Z;d++) any |= mask[mbase+d];
    return any!=0;
  } else if(mflag==1){
    const int* mp = (const int*)mask;  int any=0;
    #pragma unroll
    for(int d=0;d<D_Z;d++) any |= mp[mbase+d];
    return any!=0;
  } else {
    const long long* mp = (const long long*)mask;  long long any=0;
    #pragma unroll
    for(int d=0;d<D_Z;d++) any |= mp[mbase+d];
    return any!=0;
  }
}

// fp8x16 corner accumulate as f32x2 pairs -> v_pk_fma_f32.
__device__ __forceinline__ void corner_acc(const uint4 cv, const float wgt,
                                           f32x2* __restrict__ acc2){
  const f32x2 w2 = {wgt, wgt};
  const unsigned dw[4] = {cv.x, cv.y, cv.z, cv.w};
  #pragma unroll
  for(int j=0;j<4;j++){
    acc2[j*2+0] += w2 * __builtin_amdgcn_cvt_pk_f32_fp8(dw[j], false);
    acc2[j*2+1] += w2 * __builtin_amdgcn_cvt_pk_f32_fp8(dw[j], true);
  }
}

__device__ __forceinline__ void fma4(float4& a, const float4 t,
                                     const float4 w0, const float4 w1,
                                     const float4 w2, const float4 w3){
  a.x += t.x*w0.x + t.y*w1.x + t.z*w2.x + t.w*w3.x;
  a.y += t.x*w0.y + t.y*w1.y + t.z*w2.y + t.w*w3.y;
  a.z += t.x*w0.z + t.y*w1.z + t.z*w2.z + t.w*w3.z;
  a.w += t.x*w0.w + t.y*w1.w + t.z*w2.w + t.w*w3.w;
}

__device__ __forceinline__ void shfl4_add32(float4& a){
  a.x += __shfl_xor(a.x, 32);
  a.y += __shfl_xor(a.y, 32);
  a.z += __shfl_xor(a.z, 32);
  a.w += __shfl_xor(a.w, 32);
}

__device__ __forceinline__ float4 shfl4_xor(float4 v, int m){
  return make_float4(__shfl_xor(v.x,m), __shfl_xor(v.y,m),
                     __shfl_xor(v.z,m), __shfl_xor(v.w,m));
}

__device__ __forceinline__ float4 f4add(float4 a, float4 b){
  return make_float4(a.x+b.x, a.y+b.y, a.z+b.z, a.w+b.w);
}

// ---------------------------------------------------------------------------
// K1 = value-proj (blocks 0..524) UNION q-proj (blocks 525..1036).
// R7: vproj widened to 16 rows/block -- Wv is read once per 16 rows (W-TA
// halves, 7->3.5us); LDS-broadcast cost per row unchanged. q-proj kept at
// 32 q/block, 8 q/wave. offs -> out cols 0..63, attns -> out cols 64..95
// (dead OUT rows as staging; workspace stays ~1.08MB).
// ---------------------------------------------------------------------------
__global__ __launch_bounds__(256)
void prep_kernel(const float* __restrict__ value,
                 const float* __restrict__ Wv,
                 const float* __restrict__ bv,
                 unsigned char* __restrict__ v8,
                 const unsigned char* __restrict__ mask,
                 int* __restrict__ flag,
                 const float* __restrict__ query,
                 const float* __restrict__ query_pos,
                 const float* __restrict__ Wo, const float* __restrict__ bo,
                 const float* __restrict__ Wa, const float* __restrict__ ba,
                 float* __restrict__ out){
  __shared__ float smem[4096];               // vproj: tile[16][128]+... ; qproj: qtile[32][128]
  __shared__ float part[2048];               // vproj: kh=1 partials [16][128]
  __shared__ float lbuf[32][32];             // qproj: raw logits for softmax
  __shared__ int s_cntA, s_cntB;
  const int tid = threadIdx.x;
  const int bid = blockIdx.x;

  if(bid < VP_BLOCKS){
    // ---------------- value projection (16 rows) -> fp8 ----------------
    float* tile = smem;                      // [16][128]
    const int c   = tid & 127;
    const int kh  = tid >> 7;
    const int r0  = bid * 16;
    if(bid==0 && tid==0){ s_cntA=0; s_cntB=0; }
    {
      const float4* src = (const float4*)(value + (size_t)r0*C_DIM);
      ((float4*)tile)[tid]       = src[tid];
      ((float4*)tile)[tid + 256] = src[tid + 256];
    }
    __syncthreads();
    float acc[16];
    {
      const float bias = kh ? 0.f : bv[c];
      #pragma unroll
      for(int r=0;r<16;r++) acc[r]=bias;
    }
    {
      const float* Wp = Wv + (size_t)kh*64*C_DIM + c;
      const int k00 = kh*64;
      for(int k0=0;k0<64;k0+=4){
        const float w0 = Wp[0];
        const float w1 = Wp[C_DIM];
        const float w2 = Wp[2*C_DIM];
        const float w3 = Wp[3*C_DIM];
        #pragma unroll
        for(int r=0;r<16;r++){
          const float4 t = *(const float4*)&tile[r*C_DIM + k00+k0];
          acc[r] += t.x*w0 + t.y*w1 + t.z*w2 + t.w*w3;
        }
        Wp += 4*C_DIM;
      }
    }
    if(kh){
      #pragma unroll
      for(int r=0;r<16;r++) part[r*C_DIM + c] = acc[r];
    }
    __syncthreads();
    if(!kh){
      #pragma unroll
      for(int r=0;r<16;r++){
        const float v = acc[r] + part[r*C_DIM + c];
        const int pk = __builtin_amdgcn_cvt_pk_fp8_f32(v, v, 0, false);
        v8[(size_t)(r0+r)*C_DIM + c] = (unsigned char)(pk & 0xff);
      }
    }
    if(bid==0){
      int a=0, b=0;
      for(int i=tid;i<1024;i+=256){
        const unsigned char v = mask[i];
        if(((i&3)!=0) && v) a=1;
        if(((i&7)==4) && v) b=1;
      }
      if(a) atomicOr(&s_cntA,1);
      if(b) atomicOr(&s_cntB,1);
      __syncthreads();
      if(tid==0) flag[0] = s_cntA ? 0 : (s_cntB ? 1 : 2);
    }
  } else {
    // ---------------- query projections + softmax (32 q/block) ----------------
    const int qb = bid - VP_BLOCKS;
    const int n0 = qb * 32;
    float* qtile = smem;                     // [32][128]
    {
      const float4* qa = (const float4*)(query     + (size_t)n0*C_DIM);
      const float4* qp = (const float4*)(query_pos + (size_t)n0*C_DIM);
      #pragma unroll
      for(int j=0;j<4;j++){
        const int idx = tid + 256*j;
        const float4 A = qa[idx], B = qp[idx];
        *(float4*)&qtile[idx*4] = make_float4(A.x+B.x, A.y+B.y, A.z+B.z, A.w+B.w);
      }
    }
    __syncthreads();
    const int wi = tid >> 6;                 // wave: queries wi*8 .. wi*8+7
    const int ln = tid & 63;
    const int kh = ln >> 5;                  // k-half
    const int cg = ln & 31;                  // col-group
    float4 a[8];
    #pragma unroll
    for(int q=0;q<8;q++) a[q]=make_float4(0.f,0.f,0.f,0.f);
    if(cg < 24){
      const float* Wp; int stride; const float* bptr;
      if(cg < 16){ Wp = Wo + cg*4;      stride = 64; bptr = &bo[cg*4]; }
      else       { Wp = Wa + (cg-16)*4; stride = 32; bptr = &ba[(cg-16)*4]; }
      if(kh==0){
        const float4 bb = *(const float4*)bptr;
        #pragma unroll
        for(int q=0;q<8;q++) a[q]=bb;
      }
      Wp += (size_t)kh*64*stride;
      const float* qbase = &qtile[(size_t)wi*8*C_DIM + kh*64];
      #pragma unroll 4
      for(int k0=0;k0<64;k0+=4){
        const float4 w0 = *(const float4*)&Wp[0];
        const float4 w1 = *(const float4*)&Wp[stride];
        const float4 w2 = *(const float4*)&Wp[2*stride];
        const float4 w3 = *(const float4*)&Wp[3*stride];
        #pragma unroll
        for(int q=0;q<8;q++)
          fma4(a[q], *(const float4*)&qbase[q*C_DIM + k0], w0,w1,w2,w3);
        Wp += 4*stride;
      }
    }
    #pragma unroll
    for(int q=0;q<8;q++) shfl4_add32(a[q]);  // both kh halves now hold full sums
    if(cg < 16){
      const int c0 = cg*4;
      const int rb = n0 + wi*8 + (kh?4:0);   // kh=0 stores q0..3, kh=1 q4..7
      #pragma unroll
      for(int i=0;i<4;i++){
        const float4 v = kh ? a[4+i] : a[i];
        *(float4*)&out[(size_t)(rb+i)*C_DIM + c0] = v;
      }
    } else if(cg < 24){
      const int c0 = (cg-16)*4;
      const int rb = wi*8 + (kh?4:0);
      #pragma unroll
      for(int i=0;i<4;i++){
        const float4 v = kh ? a[4+i] : a[i];
        *(float4*)&lbuf[rb+i][c0] = v;
      }
    }
    __syncthreads();
    if(tid < 128){                           // softmax over P=8: (q, h)
      const int q = tid >> 2, h = tid & 3;
      const float* L = &lbuf[q][h*8];
      float mx = L[0];
      #pragma unroll
      for(int p=1;p<8;p++) mx = fmaxf(mx, L[p]);
      float e[8], ssum = 0.f;
      #pragma unroll
      for(int p=0;p<8;p++){ e[p] = __expf(L[p]-mx); ssum += e[p]; }
      const float inv = 1.f/ssum;
      float* dst = &out[(size_t)(n0+q)*C_DIM + 64 + h*8];
      *(float4*)dst     = make_float4(e[0]*inv, e[1]*inv, e[2]*inv, e[3]*inv);
      *(float4*)(dst+4) = make_float4(e[4]*inv, e[5]*inv, e[6]*inv, e[7]*inv);
    }
  }
}

// ---------------------------------------------------------------------------
// K2: gather + out-proj fused. R7: gather phase is LATENCY-bound (TA floor
// ~10us, VALU ~13us, measured ~45us scatter): the pp-loop is now FULLY
// unrolled so the compiler can keep ~16 corner loads in flight per wave
// (VGPR 68 -> ~100-130, plenty of headroom; R1 showed wave-count is not the
// binding resource, per-wave MLP is). Outproj output-split unchanged (Wout
// read once per block, 3-round shfl reduce-scatter).
// ---------------------------------------------------------------------------
__global__ __launch_bounds__(256)
void gather_kernel(const unsigned char* __restrict__ v8,
                   const float* __restrict__ ref,
                   const unsigned char* __restrict__ mask,
                   const int* __restrict__ flag,
                   const float* __restrict__ query,
                   const float* __restrict__ Wout,
                   const float* __restrict__ bout,
                   float* __restrict__ out){
  __shared__ float  qs[QPB][C_DIM+4];        // slot rows
  __shared__ float  offs[QPB][68];           // 68 mod 32 = 4
  __shared__ float  attns[QPB][36];
  __shared__ float2 refs[QPB][S_CAM*D_Z+1];  // 49 f2 rows
  __shared__ int    activ[QPB][S_CAM];
  __shared__ float  cinv[QPB];

  const int tid = threadIdx.x;
  const int n0  = blockIdx.x * QPB;
  const int mflag = flag[0];
  const int qi = tid >> 5;                   // query in block
  const int l  = tid & 31;                   // lane within query group

  // ---- staging: offs/attns from out rows (cols 0..95), refs, activ, cinv ----
  if(tid < 192){                             // 8q x 24 f4 = offs(16) + attns(8)
    const int q = tid/24, j = tid%24;
    const float4 v = *(const float4*)&out[(size_t)(n0+q)*C_DIM + j*4];
    if(j<16) *(float4*)&offs[q][j*4] = v;
    else     *(float4*)&attns[q][(j-16)*4] = v;
  }
  {
    const int q = tid/48, r = tid%48;        // r = s*8+p
    refs[q][r] = ((const float2*)ref)[((size_t)(r>>3)*N_Q + (n0+q))*D_Z + (r&7)];
    if(tid < 128){
      const int e1 = tid + 256;
      const int q1 = e1/48, r1 = e1%48;
      refs[q1][r1] = ((const float2*)ref)[((size_t)(r1>>3)*N_Q + (n0+q1))*D_Z + (r1&7)];
    }
  }
  if(tid < QPB*S_CAM){
    const int q2 = tid / S_CAM, s = tid % S_CAM;
    activ[q2][s] = mask_any(mask, mflag, ((size_t)s*N_Q + (n0+q2))*D_Z) ? 1 : 0;
  } else if(tid < QPB*S_CAM + QPB){
    const int q2 = tid - QPB*S_CAM;
    int c = 0;
    #pragma unroll
    for(int s=0;s<S_CAM;s++)
      c += mask_any(mask, mflag, ((size_t)s*N_Q + (n0+q2))*D_Z) ? 1 : 0;
    cinv[q2] = 1.f / fmaxf((float)c, 1.f);
  }
  __syncthreads();                           // staging reads done before out overwrite

  // ---- gather: 3 cams x 4 points per lane, fully unrolled points ----
  const int pg  = l >> 4;                    // points pg*4 .. pg*4+3
  const int sg  = (l >> 3) & 1;              // cams sg*3 .. sg*3+2
  const int ll  = l & 7;                     // 16-ch group
  const int gch = ll*16;
  const int gh  = ll >> 1;                   // head (32 ch/head)
  f32x2 acc2[8];
  #pragma unroll
  for(int i=0;i<8;i++) acc2[i] = (f32x2){0.f, 0.f};

  for(int s=sg*3; s<sg*3+3; s++){
    if(!activ[qi][s]) continue;
    const unsigned char* vb = v8 + (size_t)s*M_VAL*C_DIM + gch;
    #pragma unroll
    for(int pp=0;pp<4;pp++){                 // point p <-> z-anchor d=p (P//D==1)
      const int p = pg*4 + pp;
      const float2 r2 = refs[qi][s*8+p];
      const float ox = offs[qi][gh*16+p*2+0];
      const float oy = offs[qi][gh*16+p*2+1];
      const float x = fmaf(r2.x, (float)WF, ox - 0.5f);
      const float y = fmaf(r2.y, (float)HF, oy - 0.5f);
      const float x0f = floorf(x), y0f = floorf(y);
      const float fx = x - x0f,    fy = y - y0f;
      const int x0 = (int)x0f, y0 = (int)y0f;
      const int x1 = x0+1,     y1 = y0+1;
      const float at = attns[qi][gh*8+p];
      const float wx0 = (x0>=0 && x0<WF) ? (1.f-fx) : 0.f;
      const float wx1 = (x1>=0 && x1<WF) ? fx       : 0.f;
      const float wy0 = ((y0>=0 && y0<HF) ? (1.f-fy) : 0.f) * at;
      const float wy1 = ((y1>=0 && y1<HF) ? fy       : 0.f) * at;
      const int x0c = min(max(x0,0), WF-1), x1c = min(max(x1,0), WF-1);
      const int y0c = min(max(y0,0), HF-1), y1c = min(max(y1,0), HF-1);
      const float w00 = wx0*wy0, w01 = wx1*wy0, w10 = wx0*wy1, w11 = wx1*wy1;
      const uint4 c00 = *(const uint4*)(vb + (size_t)(y0c*WF+x0c)*C_DIM);
      const uint4 c01 = *(const uint4*)(vb + (size_t)(y0c*WF+x1c)*C_DIM);
      const uint4 c10 = *(const uint4*)(vb + (size_t)(y1c*WF+x0c)*C_DIM);
      const uint4 c11 = *(const uint4*)(vb + (size_t)(y1c*WF+x1c)*C_DIM);
      corner_acc(c00, w00, acc2);
      corner_acc(c01, w01, acc2);
      corner_acc(c10, w10, acc2);
      corner_acc(c11, w11, acc2);
    }
  }

  // ---- merge 4 (pg,sg) partials; slot rows -> LDS ----
  float* accf = (float*)acc2;
  #pragma unroll
  for(int i=0;i<16;i++) accf[i] += __shfl_xor(accf[i], 16);  // merge pt halves
  #pragma unroll
  for(int i=0;i<16;i++) accf[i] += __shfl_xor(accf[i], 8);   // merge cam halves
  if(l < 8){
    const float inv = cinv[qi];
    #pragma unroll
    for(int i=0;i<4;i++)
      *(float4*)&qs[qi][gch+i*4] = make_float4(accf[i*4+0]*inv, accf[i*4+1]*inv,
                                               accf[i*4+2]*inv, accf[i*4+3]*inv);
  }
  __syncthreads();                           // all 8 slot rows visible to all waves

  // ---- out-proj + bias + residual: output-split, Wout read once/block ----
  {
    const int wi2   = tid >> 6;              // wave -> col stripe wi2*32
    const int ln    = tid & 63;
    const int kslot = ln >> 3;               // k-subset AND final store-query
    const int cg    = ln & 7;                // f4 col within stripe
    const int c0    = wi2*32 + cg*4;
    float4 a[8];
    #pragma unroll
    for(int q=0;q<8;q++) a[q]=make_float4(0.f,0.f,0.f,0.f);
    const float* Wp = Wout + (size_t)kslot*C_DIM + c0;
    #pragma unroll 4
    for(int t=0;t<16;t++){
      const float4 w = *(const float4*)Wp;   // Wout[8t+kslot][c0..c0+3]
      const int k = 8*t + kslot;
      #pragma unroll
      for(int q=0;q<8;q++){
        const float s = qs[q][k];
        a[q].x += s*w.x; a[q].y += s*w.y; a[q].z += s*w.z; a[q].w += s*w.w;
      }
      Wp += 8*C_DIM;
    }
    // reduce-scatter over kslot lanes: query q ends at lane kslot==q.
    // mask 32 <-> q bit2
    const bool b2 = (kslot & 4) != 0;
    float4 s0 = b2 ? a[0] : a[4];            // send = half we don't keep
    float4 s1 = b2 ? a[1] : a[5];
    float4 s2 = b2 ? a[2] : a[6];
    float4 s3 = b2 ? a[3] : a[7];
    s0 = shfl4_xor(s0,32); s1 = shfl4_xor(s1,32);
    s2 = shfl4_xor(s2,32); s3 = shfl4_xor(s3,32);
    float4 r0 = f4add(b2 ? a[4] : a[0], s0);
    float4 r1 = f4add(b2 ? a[5] : a[1], s1);
    float4 r2 = f4add(b2 ? a[6] : a[2], s2);
    float4 r3 = f4add(b2 ? a[7] : a[3], s3);
    // mask 16 <-> q bit1
    const bool b1 = (kslot & 2) != 0;
    float4 t0 = b1 ? r0 : r2;
    float4 t1 = b1 ? r1 : r3;
    t0 = shfl4_xor(t0,16); t1 = shfl4_xor(t1,16);
    float4 k0 = f4add(b1 ? r2 : r0, t0);
    float4 k1 = f4add(b1 ? r3 : r1, t1);
    // mask 8 <-> q bit0
    const bool b0c = (kslot & 1) != 0;
    float4 u0 = b0c ? k0 : k1;
    u0 = shfl4_xor(u0,8);
    float4 fin = f4add(b0c ? k1 : k0, u0);
    // lane stores query kslot, cols c0..c0+3 (+bias+residual)
    const float4 bb = *(const float4*)&bout[c0];
    const float4 rq = *(const float4*)&query[(size_t)(n0+kslot)*C_DIM + c0];
    *(float4*)&out[(size_t)(n0+kslot)*C_DIM + c0] =
      make_float4(fin.x+bb.x+rq.x, fin.y+bb.y+rq.y,
                  fin.z+bb.z+rq.z, fin.w+bb.w+rq.w);
  }
}

extern "C" void kernel_launch(void* const* d_in, const int* in_sizes, int n_in,
                              void* d_out, int out_size, void* d_ws, size_t ws_size,
                              hipStream_t stream){
  const float* query     = (const float*)d_in[0];
  const float* query_pos = (const float*)d_in[1];
  const float* value     = (const float*)d_in[2];
  const float* ref       = (const float*)d_in[3];
  const unsigned char* mask = (const unsigned char*)d_in[4];
  const float* Wv   = (const float*)d_in[5];
  const float* bv   = (const float*)d_in[6];
  const float* Wo   = (const float*)d_in[7];
  const float* bo   = (const float*)d_in[8];
  const float* Wa   = (const float*)d_in[9];
  const float* ba   = (const float*)d_in[10];
  const float* Wout = (const float*)d_in[11];
  const float* bout = (const float*)d_in[12];
  float* out = (float*)d_out;

  int* flag = (int*)d_ws;
  unsigned char* v8 = (unsigned char*)((char*)d_ws + 64);  // 1,075,200 B (proven footprint)

  prep_kernel<<<VP_BLOCKS + QP_BLOCKS, 256, 0, stream>>>(
      value, Wv, bv, v8, mask, flag, query, query_pos, Wo, bo, Wa, ba, out);
  gather_kernel<<<N_Q/QPB, 256, 0, stream>>>(v8, ref, mask, flag,
                                             query, Wout, bout, out);
}